// Round 10
// baseline (153.282 us; speedup 1.0000x reference)
//
#include <hip/hip_runtime.h>
#include <hip/hip_bf16.h>
#include <math.h>

#define N_IN 85680
#define PRE_K 5000
#define POST_K 750
#define NW 79            // ceil(PRE_K/64) words
#define NPAD 5056        // NW*64
#define HSIZE 8192       // linear buckets over score-bit range (0.02, +inf)
#define CAND_MAX 8192
#define CONF_THR 0.02f
#define NMS_THR 0.4f
#define BITS_THR 0x3CA3D70Bu  // bits of smallest float > 0.02f
#define SBN 5            // super-blocks of 1024 boxes

typedef unsigned int u32;
typedef unsigned long long u64;

// column-major triangle-packed mask: word k's segment starts at base(k), holds
// rows 64k..NPAD-1. base(k) = sum_{j<k} (NPAD - 64j) = k*(5088 - 32k)  [u64 units]
__device__ __forceinline__ int cbase(int k) { return k * (5088 - 32 * k); }

// opacity barrier: prevents FMA contraction so f32 math bit-matches numpy ref
__device__ __forceinline__ float opaquef(float x) { asm volatile("" : "+v"(x)); return x; }

// monotone bucket of a score's float bits (score > CONF_THR guaranteed)
__device__ __forceinline__ u32 bucket_of(u32 bits) {
    u32 b = (bits - BITS_THR) >> 13;
    return b >= HSIZE ? (HSIZE - 1) : b;
}

// ---------------- fused histogram + suffix-scan (1 block); also zeroes bfill/validm ----------------
__global__ __launch_bounds__(1024) void histscan_kernel(const float2* __restrict__ conf2,
                                                        u32* __restrict__ bsel,
                                                        u32* __restrict__ bstart,
                                                        u32* __restrict__ bfill,
                                                        u64* __restrict__ validm) {
    __shared__ u32 h[HSIZE];
    __shared__ u32 tot[1024];
    int c = threadIdx.x;
    for (int b = c; b < HSIZE; b += 1024) h[b] = 0u;
    __syncthreads();
    for (int i = c; i < N_IN; i += 1024) {
        float s = conf2[i].y;
        if (s > CONF_THR) atomicAdd(&h[bucket_of(__float_as_uint(s))], 1u);
    }
    __syncthreads();
    u32 lh[8];
    u32 t = 0;
#pragma unroll
    for (int k = 0; k < 8; ++k) { lh[k] = h[c * 8 + k]; t += lh[k]; }
    tot[c] = t;
    __syncthreads();
    for (int d = 1; d < 1024; d <<= 1) {
        u32 v = tot[c] + ((c + d < 1024) ? tot[c + d] : 0u);
        __syncthreads();
        tot[c] = v;
        __syncthreads();
    }
    u32 above = (c + 1 < 1024) ? tot[c + 1] : 0u;
    u32 s = above;
    for (int k = 7; k >= 0; --k) { bstart[c * 8 + k] = s; s += lh[k]; }
    if (above < PRE_K && above + t >= PRE_K) {
        u32 cum = above;
        for (int k = 7; k >= 0; --k) {
            cum += lh[k];
            if (cum >= PRE_K) { bsel[0] = (u32)(c * 8 + k); break; }
        }
    }
    if (c == 0 && tot[0] < PRE_K) bsel[0] = 0u;
    for (int b = c; b < HSIZE; b += 1024) bfill[b] = 0u;
    if (c < 128) validm[c] = 0ull;
}

// ---------------- scatter candidates bucket-grouped ----------------
__global__ __launch_bounds__(256) void compact_kernel(const float2* __restrict__ conf2,
                                                      const u32* __restrict__ bsel,
                                                      const u32* __restrict__ bstart,
                                                      u32* __restrict__ bfill,
                                                      u64* __restrict__ cand) {
    int i = blockIdx.x * 256 + threadIdx.x;
    if (i >= N_IN) return;
    float sc = conf2[i].y;
    if (!(sc > CONF_THR)) return;
    u32 bits = __float_as_uint(sc);
    u32 b = bucket_of(bits);
    if (b < bsel[0]) return;
    u32 pos = bstart[b] + atomicAdd(&bfill[b], 1u);
    if (pos < CAND_MAX) cand[pos] = ((u64)bits << 32) | (u64)(u32)(~(u32)i);
}

// ---------------- fused: exact rank within bucket + decode -> rows/boxes/validm ----------------
__global__ __launch_bounds__(256) void rankdec_kernel(const u64* __restrict__ cand,
                                                      const u32* __restrict__ bstart,
                                                      const u32* __restrict__ bfill,
                                                      const u32* __restrict__ bsel,
                                                      const float4* __restrict__ loc4,
                                                      const float4* __restrict__ pri4,
                                                      const float* __restrict__ lmk,
                                                      const int* __restrict__ imw,
                                                      const int* __restrict__ imh,
                                                      float4* __restrict__ rows4,
                                                      float4* __restrict__ boxes,
                                                      u64* __restrict__ validm) {
    u32 bs = bsel[0];
    u32 total = bstart[bs] + bfill[bs];
    if (total > CAND_MAX) total = CAND_MAX;
    float W = (float)(*imw), H = (float)(*imh);
    for (u32 s = blockIdx.x * blockDim.x + threadIdx.x; s < total;
         s += gridDim.x * blockDim.x) {
        u64 key = cand[s];
        u32 b = bucket_of((u32)(key >> 32));
        u32 st = bstart[b];
        u32 en = st + bfill[b];
        if (en > CAND_MAX) en = CAND_MAX;
        u32 r = st;
        for (u32 j = st; j < en; ++j) r += (cand[j] > key) ? 1u : 0u;
        if (r >= PRE_K) continue;
        u32 i = ~(u32)key;
        float score = __uint_as_float((u32)(key >> 32));
        float4 L = loc4[i];
        float4 P = pri4[i];
        float cx = P.x + opaquef((L.x * 0.1f) * P.z);
        float cy = P.y + opaquef((L.y * 0.1f) * P.w);
        float bw = P.z * (float)exp((double)(L.z * 0.2f));
        float bh = P.w * (float)exp((double)(L.w * 0.2f));
        float hw = opaquef(bw * 0.5f), hh = opaquef(bh * 0.5f);
        float x0 = (cx - hw) * W, y0 = (cy - hh) * H;
        float x1 = (cx + hw) * W, y1 = (cy + hh) * H;
        boxes[r] = make_float4(x0, y0, x1, y1);
        float lm[10];
#pragma unroll
        for (int p = 0; p < 5; ++p) {
            float2 q = ((const float2*)lmk)[(size_t)i * 5 + p];
            lm[2 * p]     = (P.x + opaquef((q.x * 0.1f) * P.z)) * W;
            lm[2 * p + 1] = (P.y + opaquef((q.y * 0.1f) * P.w)) * H;
        }
        float4* row = rows4 + (size_t)r * 4;
        row[0] = make_float4(x0, y0, x1, y1);
        row[1] = make_float4(score, lm[0], lm[1], lm[2]);
        row[2] = make_float4(lm[3], lm[4], lm[5], lm[6]);
        row[3] = make_float4(lm[7], lm[8], lm[9], 0.f);
        atomicOr(&validm[r >> 6], 1ull << (r & 63));
    }
}

// ---------------- symmetric IoU bitmask, column-major triangle-packed ----------------
// Block (rc,cc), cc<=rc: row i=rc*64+t, word cc. Write cmask[cbase(cc)+(i-64cc)]
// (consecutive t -> consecutive u64 -> coalesced).
__global__ __launch_bounds__(64) void mask_kernel(const float4* __restrict__ boxes,
                                                  u64* __restrict__ cmask) {
    int rem = blockIdx.x, rc = 0;
    while (rem >= rc + 1) { rem -= rc + 1; ++rc; }
    int cc = rem;
    __shared__ float4 cb[64];
    int t = threadIdx.x;
    cb[t] = boxes[cc * 64 + t];
    int i = rc * 64 + t;
    float4 bi = boxes[i];
    __syncthreads();
    float areai = (bi.z - bi.x) * (bi.w - bi.y);
    u64 word = 0ull;
#pragma unroll 4
    for (int k = 0; k < 64; ++k) {
        float4 bj = cb[k];
        float areaj = (bj.z - bj.x) * (bj.w - bj.y);
        float ltx = fmaxf(bi.x, bj.x), lty = fmaxf(bi.y, bj.y);
        float rbx = fminf(bi.z, bj.z), rby = fminf(bi.w, bj.w);
        float wx = fmaxf(rbx - ltx, 0.f), wy = fmaxf(rby - lty, 0.f);
        float inter = opaquef(wx * wy);
        float uni = fmaxf(areai + areaj - inter, 1e-12f);
        float iou = inter / uni;
        if (iou > NMS_THR) word |= (1ull << k);
    }
    if (i < PRE_K) cmask[(size_t)(cbase(cc) + (i - 64 * cc))] = word;
}

// predicated coalesced row-word load into an individually-named register
#define RL(K)                                                                  \
    u64 r##K = 0ull;                                                           \
    if (rowok && (K) <= wave) {                                                \
        int w_ = wbase + (K);                                                  \
        r##K = cmask[(size_t)(cbase(w_) + tid - 64 * (K))];                    \
        if ((K) == wave) r##K &= lm;                                           \
    }

// ---------------- Jacobi-fixpoint greedy NMS + fused scatter (1 block, 1024 thr) ---------
// keep_i = valid_i & ~OR_{j<i}(keep_j & iou_ij>thr); Jacobi converges in
// <= suppression-chain depth rounds. Thread tid owns box sb*1024+tid; its 16
// masked row-words live in 16 NAMED u64 registers, loaded COALESCED from the
// column-major cmask; keep vector = 16 u64 in LDS (broadcast reads).
__global__ __launch_bounds__(1024) void reduce_scatter_kernel(const u64* __restrict__ cmask,
                                                              const u64* __restrict__ validm,
                                                              const float* __restrict__ rows,
                                                              float* __restrict__ out) {
    int tid = threadIdx.x;
    int wave = tid >> 6, lane = tid & 63;
    __shared__ u64 keepAll[96];
    __shared__ u64 keepL[16];
    __shared__ u32 flags[2];
    __shared__ u32 wpref[96];
    __shared__ u32 totsh;
    for (int k = tid; k < 96; k += 1024) keepAll[k] = 0ull;
    if (tid < 2) flags[tid] = 0u;
    if (tid == 0) totsh = 0u;
    __syncthreads();
    u64 lm = (1ull << lane) - 1ull;

    for (int sb = 0; sb < SBN; ++sb) {
        int i = sb * 1024 + tid;
        int wbase = sb * 16;
        int nwloc = NW - wbase; if (nwloc > 16) nwloc = 16;
        bool wactive = (wave < nwloc);
        bool rowok = (i < PRE_K);
        int iw = wbase + wave;             // my global word (valid when rowok)
        // frozen suppression from finalized super-blocks (coalesced per word)
        u64 fr = 0ull;
        for (int w2 = 0; w2 < wbase; ++w2) {
            if (rowok) fr |= keepAll[w2] & cmask[(size_t)(cbase(w2) + i - 64 * w2)];
        }
        // my 16 row-words, registers, coalesced loads
        RL(0)  RL(1)  RL(2)  RL(3)  RL(4)  RL(5)  RL(6)  RL(7)
        RL(8)  RL(9)  RL(10) RL(11) RL(12) RL(13) RL(14) RL(15)
        bool okv = rowok && wactive && ((validm[iw] >> lane) & 1ull) && (fr == 0ull);
        u64 bw0 = __ballot(okv);
        if (lane == 0 && wave < 16) keepL[wave] = wactive ? bw0 : 0ull;
        __syncthreads();
        int p = 0;
        for (int it = 0; it < 1200; ++it) {
            u64 sup = ((keepL[0] & r0) | (keepL[1] & r1)) | ((keepL[2] & r2) | (keepL[3] & r3));
            sup |= ((keepL[4] & r4) | (keepL[5] & r5)) | ((keepL[6] & r6) | (keepL[7] & r7));
            sup |= ((keepL[8] & r8) | (keepL[9] & r9)) | ((keepL[10] & r10) | (keepL[11] & r11));
            sup |= ((keepL[12] & r12) | (keepL[13] & r13)) | ((keepL[14] & r14) | (keepL[15] & r15));
            bool nb = okv && (sup == 0ull);
            u64 nword = __ballot(nb);
            bool ch = (lane == 0) && wactive && (nword != keepL[wave]);
            __syncthreads();
            if (lane == 0 && wactive) keepL[wave] = nword;
            if (ch) atomicOr(&flags[p], 1u);
            if (tid == 0) flags[p ^ 1] = 0u;
            __syncthreads();
            if (flags[p] == 0u) break;
            p ^= 1;
        }
        if (lane == 0 && wactive) keepAll[wbase + wave] = keepL[wave];
        __syncthreads();
        if (tid == 0) {
            u32 s = 0;
            for (int k = 0; k < nwloc; ++k) s += (u32)__popcll(keepL[k]);
            totsh += s;
        }
        __syncthreads();
        if (totsh >= POST_K || wbase + nwloc >= NW) break;
    }

    // word-prefix ranks
    if (tid == 0) {
        u32 s = 0;
        for (int w = 0; w < NW; ++w) { wpref[w] = s; s += (u32)__popcll(keepAll[w]); }
        wpref[NW] = s;
    }
    __syncthreads();
    u32 totk = wpref[NW]; if (totk > POST_K) totk = POST_K;
    for (int r = tid; r < PRE_K; r += 1024) {
        int w = r >> 6, b = r & 63;
        u64 kw = keepAll[w];
        if ((kw >> b) & 1ull) {
            u32 rank = wpref[w] + (u32)__popcll(kw & ((1ull << b) - 1ull));
            if (rank < POST_K) {
                const float* src = rows + (size_t)r * 16;
                float* dst = out + (size_t)rank * 15;
#pragma unroll
                for (int c = 0; c < 15; ++c) dst[c] = src[c];
            }
        }
    }
    for (int r = (int)totk + tid; r < POST_K; r += 1024) {
        float* dst = out + (size_t)r * 15;
#pragma unroll
        for (int c = 0; c < 15; ++c) dst[c] = 0.f;
    }
}

extern "C" void kernel_launch(void* const* d_in, const int* in_sizes, int n_in,
                              void* d_out, int out_size, void* d_ws, size_t ws_size,
                              hipStream_t stream) {
    const float* loc = (const float*)d_in[0];
    const float2* conf2 = (const float2*)d_in[1];
    const float* lmk = (const float*)d_in[2];
    const float* pri = (const float*)d_in[3];
    const int* imw = (const int*)d_in[4];
    const int* imh = (const int*)d_in[5];
    float* out = (float*)d_out;
    char* base = (char*)d_ws;

    // workspace layout (bytes); total 2,184,768 (< 3,808,896 proven in R3-R9)
    u32* bfill  = (u32*)(base + 32768);     //  32768  (zeroed by histscan)
    u32* bsel   = (u32*)(base + 65536);     //  64     (always written by histscan)
    u64* validm = (u64*)(base + 65600);     //  1024   (zeroed by histscan)
    u32* bstart = (u32*)(base + 67648);     //  32768
    u64* cand   = (u64*)(base + 100416);    //  65536
    float* rows = (float*)(base + 165952);  //  320000 (5000 x 16)
    float4* boxes = (float4*)(base + 485952); // 80896 (NPAD x 16)
    u64* cmask  = (u64*)(base + 566848);    //  1617920 (202240 u64, triangle-packed)

    histscan_kernel<<<1, 1024, 0, stream>>>(conf2, bsel, bstart, bfill, validm);
    compact_kernel<<<(N_IN + 255) / 256, 256, 0, stream>>>(conf2, bsel, bstart, bfill, cand);
    rankdec_kernel<<<24, 256, 0, stream>>>(cand, bstart, bfill, bsel, (const float4*)loc,
                                           (const float4*)pri, lmk, imw, imh,
                                           (float4*)rows, boxes, validm);
    mask_kernel<<<NW * (NW + 1) / 2, 64, 0, stream>>>(boxes, cmask);
    reduce_scatter_kernel<<<1, 1024, 0, stream>>>(cmask, validm, rows, out);
}

// Round 11
// 139.832 us; speedup vs baseline: 1.0962x; 1.0962x over previous
//
#include <hip/hip_runtime.h>
#include <hip/hip_bf16.h>
#include <math.h>

#define N_IN 85680
#define PRE_K 5000
#define POST_K 750
#define NW 79            // ceil(PRE_K/64) words
#define NPAD 5056        // NW*64
#define HSIZE 8192       // linear buckets over score-bit range (0.02, +inf)
#define CAND_MAX 8192
#define CONF_THR 0.02f
#define NMS_THR 0.4f
#define BITS_THR 0x3CA3D70Bu  // bits of smallest float > 0.02f
#define SBN 5            // super-blocks of 1024 boxes

typedef unsigned int u32;
typedef unsigned long long u64;

// column-major triangle-packed mask: word k's segment starts at cbase(k), holds
// rows 64k..NPAD-1. cbase(k) = sum_{j<k} (NPAD - 64j) = k*(5088 - 32k)  [u64 units]
__device__ __forceinline__ int cbase(int k) { return k * (5088 - 32 * k); }

// opacity barrier: prevents FMA contraction so f32 math bit-matches numpy ref
__device__ __forceinline__ float opaquef(float x) { asm volatile("" : "+v"(x)); return x; }

// monotone bucket of a score's float bits (score > CONF_THR guaranteed)
__device__ __forceinline__ u32 bucket_of(u32 bits) {
    u32 b = (bits - BITS_THR) >> 13;
    return b >= HSIZE ? (HSIZE - 1) : b;
}

// ---------------- fused histogram + suffix-scan (1 block); also zeroes bfill/validm ----------------
__global__ __launch_bounds__(1024) void histscan_kernel(const float2* __restrict__ conf2,
                                                        u32* __restrict__ bsel,
                                                        u32* __restrict__ bstart,
                                                        u32* __restrict__ bfill,
                                                        u64* __restrict__ validm) {
    __shared__ u32 h[HSIZE];
    __shared__ u32 tot[1024];
    int c = threadIdx.x;
    for (int b = c; b < HSIZE; b += 1024) h[b] = 0u;
    __syncthreads();
    for (int i = c; i < N_IN; i += 1024) {
        float s = conf2[i].y;
        if (s > CONF_THR) atomicAdd(&h[bucket_of(__float_as_uint(s))], 1u);
    }
    __syncthreads();
    u32 lh[8];
    u32 t = 0;
#pragma unroll
    for (int k = 0; k < 8; ++k) { lh[k] = h[c * 8 + k]; t += lh[k]; }
    tot[c] = t;
    __syncthreads();
    for (int d = 1; d < 1024; d <<= 1) {
        u32 v = tot[c] + ((c + d < 1024) ? tot[c + d] : 0u);
        __syncthreads();
        tot[c] = v;
        __syncthreads();
    }
    u32 above = (c + 1 < 1024) ? tot[c + 1] : 0u;
    u32 s = above;
    for (int k = 7; k >= 0; --k) { bstart[c * 8 + k] = s; s += lh[k]; }
    if (above < PRE_K && above + t >= PRE_K) {
        u32 cum = above;
        for (int k = 7; k >= 0; --k) {
            cum += lh[k];
            if (cum >= PRE_K) { bsel[0] = (u32)(c * 8 + k); break; }
        }
    }
    if (c == 0 && tot[0] < PRE_K) bsel[0] = 0u;
    for (int b = c; b < HSIZE; b += 1024) bfill[b] = 0u;
    if (c < 128) validm[c] = 0ull;
}

// ---------------- scatter candidates bucket-grouped ----------------
__global__ __launch_bounds__(256) void compact_kernel(const float2* __restrict__ conf2,
                                                      const u32* __restrict__ bsel,
                                                      const u32* __restrict__ bstart,
                                                      u32* __restrict__ bfill,
                                                      u64* __restrict__ cand) {
    int i = blockIdx.x * 256 + threadIdx.x;
    if (i >= N_IN) return;
    float sc = conf2[i].y;
    if (!(sc > CONF_THR)) return;
    u32 bits = __float_as_uint(sc);
    u32 b = bucket_of(bits);
    if (b < bsel[0]) return;
    u32 pos = bstart[b] + atomicAdd(&bfill[b], 1u);
    if (pos < CAND_MAX) cand[pos] = ((u64)bits << 32) | (u64)(u32)(~(u32)i);
}

// ---------------- fused: exact rank within bucket + decode -> rows/boxes/validm ----------------
__global__ __launch_bounds__(256) void rankdec_kernel(const u64* __restrict__ cand,
                                                      const u32* __restrict__ bstart,
                                                      const u32* __restrict__ bfill,
                                                      const u32* __restrict__ bsel,
                                                      const float4* __restrict__ loc4,
                                                      const float4* __restrict__ pri4,
                                                      const float* __restrict__ lmk,
                                                      const int* __restrict__ imw,
                                                      const int* __restrict__ imh,
                                                      float4* __restrict__ rows4,
                                                      float4* __restrict__ boxes,
                                                      u64* __restrict__ validm) {
    u32 bs = bsel[0];
    u32 total = bstart[bs] + bfill[bs];
    if (total > CAND_MAX) total = CAND_MAX;
    float W = (float)(*imw), H = (float)(*imh);
    for (u32 s = blockIdx.x * blockDim.x + threadIdx.x; s < total;
         s += gridDim.x * blockDim.x) {
        u64 key = cand[s];
        u32 b = bucket_of((u32)(key >> 32));
        u32 st = bstart[b];
        u32 en = st + bfill[b];
        if (en > CAND_MAX) en = CAND_MAX;
        u32 r = st;
        for (u32 j = st; j < en; ++j) r += (cand[j] > key) ? 1u : 0u;
        if (r >= PRE_K) continue;
        u32 i = ~(u32)key;
        float score = __uint_as_float((u32)(key >> 32));
        float4 L = loc4[i];
        float4 P = pri4[i];
        float cx = P.x + opaquef((L.x * 0.1f) * P.z);
        float cy = P.y + opaquef((L.y * 0.1f) * P.w);
        float bw = P.z * (float)exp((double)(L.z * 0.2f));
        float bh = P.w * (float)exp((double)(L.w * 0.2f));
        float hw = opaquef(bw * 0.5f), hh = opaquef(bh * 0.5f);
        float x0 = (cx - hw) * W, y0 = (cy - hh) * H;
        float x1 = (cx + hw) * W, y1 = (cy + hh) * H;
        boxes[r] = make_float4(x0, y0, x1, y1);
        float lm[10];
#pragma unroll
        for (int p = 0; p < 5; ++p) {
            float2 q = ((const float2*)lmk)[(size_t)i * 5 + p];
            lm[2 * p]     = (P.x + opaquef((q.x * 0.1f) * P.z)) * W;
            lm[2 * p + 1] = (P.y + opaquef((q.y * 0.1f) * P.w)) * H;
        }
        float4* row = rows4 + (size_t)r * 4;
        row[0] = make_float4(x0, y0, x1, y1);
        row[1] = make_float4(score, lm[0], lm[1], lm[2]);
        row[2] = make_float4(lm[3], lm[4], lm[5], lm[6]);
        row[3] = make_float4(lm[7], lm[8], lm[9], 0.f);
        atomicOr(&validm[r >> 6], 1ull << (r & 63));
    }
}

// ---------------- symmetric IoU bitmask, column-major triangle-packed ----------------
__global__ __launch_bounds__(64) void mask_kernel(const float4* __restrict__ boxes,
                                                  u64* __restrict__ cmask) {
    int rem = blockIdx.x, rc = 0;
    while (rem >= rc + 1) { rem -= rc + 1; ++rc; }
    int cc = rem;
    __shared__ float4 cb[64];
    int t = threadIdx.x;
    cb[t] = boxes[cc * 64 + t];
    int i = rc * 64 + t;
    float4 bi = boxes[i];
    __syncthreads();
    float areai = (bi.z - bi.x) * (bi.w - bi.y);
    u64 word = 0ull;
#pragma unroll 4
    for (int k = 0; k < 64; ++k) {
        float4 bj = cb[k];
        float areaj = (bj.z - bj.x) * (bj.w - bj.y);
        float ltx = fmaxf(bi.x, bj.x), lty = fmaxf(bi.y, bj.y);
        float rbx = fminf(bi.z, bj.z), rby = fminf(bi.w, bj.w);
        float wx = fmaxf(rbx - ltx, 0.f), wy = fmaxf(rby - lty, 0.f);
        float inter = opaquef(wx * wy);
        float uni = fmaxf(areai + areaj - inter, 1e-12f);
        float iou = inter / uni;
        if (iou > NMS_THR) word |= (1ull << k);
    }
    if (i < PRE_K) cmask[(size_t)(cbase(cc) + (i - 64 * cc))] = word;
}

// ---------------- Jacobi-fixpoint greedy NMS + fused scatter (1 block, 1024 thr) ---------
// keep_i = valid_i & ~OR_{j<i}(keep_j & iou_ij>thr); Jacobi converges in
// <= suppression-chain depth rounds. Thread tid owns box sb*1024+tid; its 16
// masked row-words live in LDS rl[k][tid] (128 KiB — NOT registers: at 1024
// threads the 64-VGPR cap forces scratch spill, the R10 failure), loaded once
// coalesced from column-major cmask; keep vector = 16 u64 in LDS (broadcast).
__global__ __launch_bounds__(1024) void reduce_scatter_kernel(const u64* __restrict__ cmask,
                                                              const u64* __restrict__ validm,
                                                              const float* __restrict__ rows,
                                                              float* __restrict__ out) {
    int tid = threadIdx.x;
    int wave = tid >> 6, lane = tid & 63;
    __shared__ u64 rl[16 * 1024];   // [k][tid] row words, 128 KiB
    __shared__ u64 keepAll[96];
    __shared__ u64 keepL[16];
    __shared__ u32 flags[2];
    __shared__ u32 wpref[96];
    __shared__ u32 totsh;
    for (int k = tid; k < 96; k += 1024) keepAll[k] = 0ull;
    if (tid < 2) flags[tid] = 0u;
    if (tid == 0) totsh = 0u;
    __syncthreads();
    u64 lm = (1ull << lane) - 1ull;

    for (int sb = 0; sb < SBN; ++sb) {
        int i = sb * 1024 + tid;
        int wbase = sb * 16;
        int nwloc = NW - wbase; if (nwloc > 16) nwloc = 16;
        bool wactive = (wave < nwloc);
        bool rowok = (i < PRE_K);
        // frozen suppression from finalized super-blocks (coalesced per word)
        u64 fr = 0ull;
        for (int w2 = 0; w2 < wbase; ++w2) {
            if (rowok) fr |= keepAll[w2] & cmask[(size_t)(cbase(w2) + i - 64 * w2)];
        }
        // load my 16 row-words into LDS, coalesced (note: i - 64*(wbase+k) == tid - 64k)
#pragma unroll
        for (int k = 0; k < 16; ++k) {
            u64 v = 0ull;
            if (rowok && k <= wave) {
                int w_ = wbase + k;
                v = cmask[(size_t)(cbase(w_) + tid - 64 * k)];
                if (k == wave) v &= lm;
            }
            rl[k * 1024 + tid] = v;
        }
        bool okv = rowok && wactive && ((validm[wbase + wave] >> lane) & 1ull) && (fr == 0ull);
        u64 bw0 = __ballot(okv);
        if (lane == 0 && wave < 16) keepL[wave] = wactive ? bw0 : 0ull;
        __syncthreads();
        int p = 0;
        for (int it = 0; it < 1200; ++it) {
            u64 sup = 0ull;
#pragma unroll
            for (int k = 0; k < 16; ++k) sup |= keepL[k] & rl[k * 1024 + tid];
            bool nb = okv && (sup == 0ull);
            u64 nword = __ballot(nb);
            bool ch = (lane == 0) && wactive && (nword != keepL[wave]);
            __syncthreads();
            if (lane == 0 && wactive) keepL[wave] = nword;
            if (ch) atomicOr(&flags[p], 1u);
            if (tid == 0) flags[p ^ 1] = 0u;
            __syncthreads();
            if (flags[p] == 0u) break;
            p ^= 1;
        }
        if (lane == 0 && wactive) keepAll[wbase + wave] = keepL[wave];
        __syncthreads();
        if (tid == 0) {
            u32 s = 0;
            for (int k = 0; k < nwloc; ++k) s += (u32)__popcll(keepL[k]);
            totsh += s;
        }
        __syncthreads();
        if (totsh >= POST_K || wbase + nwloc >= NW) break;
    }

    // word-prefix ranks
    if (tid == 0) {
        u32 s = 0;
        for (int w = 0; w < NW; ++w) { wpref[w] = s; s += (u32)__popcll(keepAll[w]); }
        wpref[NW] = s;
    }
    __syncthreads();
    u32 totk = wpref[NW]; if (totk > POST_K) totk = POST_K;
    for (int r = tid; r < PRE_K; r += 1024) {
        int w = r >> 6, b = r & 63;
        u64 kw = keepAll[w];
        if ((kw >> b) & 1ull) {
            u32 rank = wpref[w] + (u32)__popcll(kw & ((1ull << b) - 1ull));
            if (rank < POST_K) {
                const float* src = rows + (size_t)r * 16;
                float* dst = out + (size_t)rank * 15;
#pragma unroll
                for (int c = 0; c < 15; ++c) dst[c] = src[c];
            }
        }
    }
    for (int r = (int)totk + tid; r < POST_K; r += 1024) {
        float* dst = out + (size_t)r * 15;
#pragma unroll
        for (int c = 0; c < 15; ++c) dst[c] = 0.f;
    }
}

extern "C" void kernel_launch(void* const* d_in, const int* in_sizes, int n_in,
                              void* d_out, int out_size, void* d_ws, size_t ws_size,
                              hipStream_t stream) {
    const float* loc = (const float*)d_in[0];
    const float2* conf2 = (const float2*)d_in[1];
    const float* lmk = (const float*)d_in[2];
    const float* pri = (const float*)d_in[3];
    const int* imw = (const int*)d_in[4];
    const int* imh = (const int*)d_in[5];
    float* out = (float*)d_out;
    char* base = (char*)d_ws;

    // workspace layout (bytes); total 2,184,768 (< 3,808,896 proven in R3-R10)
    u32* bfill  = (u32*)(base + 32768);     //  32768  (zeroed by histscan)
    u32* bsel   = (u32*)(base + 65536);     //  64     (always written by histscan)
    u64* validm = (u64*)(base + 65600);     //  1024   (zeroed by histscan)
    u32* bstart = (u32*)(base + 67648);     //  32768
    u64* cand   = (u64*)(base + 100416);    //  65536
    float* rows = (float*)(base + 165952);  //  320000 (5000 x 16)
    float4* boxes = (float4*)(base + 485952); // 80896 (NPAD x 16)
    u64* cmask  = (u64*)(base + 566848);    //  1617920 (202240 u64, triangle-packed)

    histscan_kernel<<<1, 1024, 0, stream>>>(conf2, bsel, bstart, bfill, validm);
    compact_kernel<<<(N_IN + 255) / 256, 256, 0, stream>>>(conf2, bsel, bstart, bfill, cand);
    rankdec_kernel<<<24, 256, 0, stream>>>(cand, bstart, bfill, bsel, (const float4*)loc,
                                           (const float4*)pri, lmk, imw, imh,
                                           (float4*)rows, boxes, validm);
    mask_kernel<<<NW * (NW + 1) / 2, 64, 0, stream>>>(boxes, cmask);
    reduce_scatter_kernel<<<1, 1024, 0, stream>>>(cmask, validm, rows, out);
}